// Round 8
// baseline (2941.643 us; speedup 1.0000x reference)
//
#include <hip/hip_runtime.h>
#include <stdint.h>

// ---------------- problem constants ----------------
#define H_DIM 2048
#define I_DIM 1024
#define K_BASIS 8
#define E_NUM 128
#define TOPK 4
#define T_TOK 8192

typedef unsigned short ushort_t;
typedef short bf16x8 __attribute__((ext_vector_type(8)));
typedef float f32x4 __attribute__((ext_vector_type(4)));
typedef float f32x2 __attribute__((ext_vector_type(2)));

__device__ __forceinline__ ushort_t f2bf(float f) {
  uint32_t u = __float_as_uint(f);
  uint32_t r = (u + 0x7FFFu + ((u >> 16) & 1u)) >> 16;
  return (ushort_t)r;
}
__device__ __forceinline__ float bf2f(ushort_t b) {
  return __uint_as_float(((uint32_t)b) << 16);
}

__device__ __forceinline__ void gload_lds16(const void* g, void* l) {
  __builtin_amdgcn_global_load_lds(
      (const __attribute__((address_space(1))) void*)g,
      (__attribute__((address_space(3))) void*)l, 16, 0, 0);
}

// ---------------- prep: fp32 -> bf16 hi/lo (no transpose, for x) ----------------
__global__ void k_convert_split(const float* __restrict__ in, ushort_t* __restrict__ hi,
                                ushort_t* __restrict__ lo, int n4) {
  int stride = gridDim.x * blockDim.x;
  for (int i = blockIdx.x * blockDim.x + threadIdx.x; i < n4; i += stride) {
    float4 v = ((const float4*)in)[i];
    ushort4 h, l;
    h.x = f2bf(v.x); l.x = f2bf(v.x - bf2f(h.x));
    h.y = f2bf(v.y); l.y = f2bf(v.y - bf2f(h.y));
    h.z = f2bf(v.z); l.z = f2bf(v.z - bf2f(h.z));
    h.w = f2bf(v.w); l.w = f2bf(v.w - bf2f(h.w));
    ((ushort4*)hi)[i] = h;
    ((ushort4*)lo)[i] = l;
  }
}

// ---------------- prep: fp32 submatrix -> bf16 hi/lo transposed ----------------
// in: base pointer (possibly offset into a larger matrix), row stride C.
// grid.x*32 columns, grid.y*32 rows are transposed. Output [cols][R] with ld R.
__global__ void k_transpose_split(const float* __restrict__ in, ushort_t* __restrict__ hi,
                                  ushort_t* __restrict__ lo, int R, int C) {
  __shared__ float tile[32][33];
  int c0 = blockIdx.x * 32, r0 = blockIdx.y * 32;
  int tx = threadIdx.x, ty = threadIdx.y;
#pragma unroll
  for (int i = 0; i < 4; ++i) {
    int r = ty + i * 8;
    tile[r][tx] = in[(size_t)(r0 + r) * C + (c0 + tx)];
  }
  __syncthreads();
#pragma unroll
  for (int i = 0; i < 4; ++i) {
    int oc = ty + i * 8;
    float v = tile[tx][oc];
    size_t o = (size_t)(c0 + oc) * R + (r0 + tx);
    ushort_t h = f2bf(v);
    hi[o] = h;
    lo[o] = f2bf(v - bf2f(h));
  }
}

// ---------------- router epilogue: softmax + top4 + renorm + wk[t,k] ----------------
__global__ void k_router(const float* __restrict__ logits, const float* __restrict__ amps,
                         const float* __restrict__ escale, float* __restrict__ wk) {
  int wave = threadIdx.x >> 6;
  int lane = threadIdx.x & 63;
  int tok = blockIdx.x * 4 + wave;
  const float* lg = logits + (size_t)tok * E_NUM;
  float l0 = lg[lane], l1 = lg[lane + 64];
  float m = fmaxf(l0, l1);
#pragma unroll
  for (int s = 32; s >= 1; s >>= 1) m = fmaxf(m, __shfl_xor(m, s));
  float e0 = __expf(l0 - m), e1 = __expf(l1 - m);
  float sum = e0 + e1;
#pragma unroll
  for (int s = 32; s >= 1; s >>= 1) sum += __shfl_xor(sum, s);
  float p0 = e0 / sum, p1 = e1 / sum;

  float selp[TOPK]; int seli[TOPK];
  float ptop = 0.f;
#pragma unroll
  for (int it = 0; it < TOPK; ++it) {
    float v; int idx;
    if (p0 >= p1) { v = p0; idx = lane; } else { v = p1; idx = lane + 64; }
#pragma unroll
    for (int s = 32; s >= 1; s >>= 1) {
      float ov = __shfl_xor(v, s);
      int oi = __shfl_xor(idx, s);
      if (ov > v || (ov == v && oi < idx)) { v = ov; idx = oi; }
    }
    selp[it] = v; seli[it] = idx; ptop += v;
    if (idx < 64) { if (lane == idx) p0 = -1.f; }
    else          { if (lane == idx - 64) p1 = -1.f; }
  }
  float denom = ptop + 1e-8f;

  int k = lane & 7;
  float acc = 0.f;
#pragma unroll
  for (int it = 0; it < TOPK; ++it) {
    int e = seli[it];
    float w = selp[it] / denom * escale[e];
    float a0 = amps[(size_t)e * 16 + k * 2];
    float a1 = amps[(size_t)e * 16 + k * 2 + 1];
    float p = a0 * a0 + a1 * a1;
    float ps = p;
#pragma unroll
    for (int s = 1; s < 8; s <<= 1) ps += __shfl_xor(ps, s);
    acc += w * (p / (ps + 1e-8f));
  }
  if (lane < 8) wk[(size_t)tok * 8 + lane] = acc;
}

// ---------------- GEMM core ----------------
// C[M,N] = A[M,K] * B[N,K]^T, split-bf16 3-product (segs: hi*hi, lo*hi, hi*lo).
// 128x128 tile, BK=32, 512 threads (8 waves, 2x4), per-wave 64x32.
// EPI: 0 = Cf write, 1 = Cf +=,
//      2 = silu(g)*u -> Ohi/Olo bf16 split store,
//      4 = Ohi/Olo (+)= wk[t,chunk]*silu(g)*u  (hi/lo RMW accumulator; accum=0
//          on the first chunk writes fresh).
template<int NMATS, int EPI>
__global__ __launch_bounds__(512) void k_gemm(
    const ushort_t* __restrict__ A0, const ushort_t* __restrict__ A1,
    const ushort_t* __restrict__ B00, const ushort_t* __restrict__ B01,
    const ushort_t* __restrict__ B10, const ushort_t* __restrict__ B11,
    const float* __restrict__ wk,
    float* __restrict__ Cf,
    ushort_t* __restrict__ Ohi, ushort_t* __restrict__ Olo,
    int K, int out_ld, int chunk, int accum)
{
  __shared__ __align__(16) ushort_t lA[128 * 32];
  __shared__ __align__(16) ushort_t lB0[128 * 32];
  __shared__ __align__(16) ushort_t lB1[(NMATS == 2) ? 128 * 32 : 8];
  __shared__ float lwk[(EPI == 4) ? 128 * 8 : 8];

  const int tid = threadIdx.x;
  const int lane = tid & 63;
  const int wid = tid >> 6;
  const int wr = wid >> 2;
  const int wc = wid & 3;
  const int m0 = blockIdx.x * 128;
  const int n0 = blockIdx.y * 128;

  const int srow = tid >> 2;
  const int skp = (tid & 3) * 8;
  const int lrow = lane & 15;
  const int kg = (lane >> 4) * 8;

  if (EPI == 4) {
    f32x2 v = *(const f32x2*)(wk + (size_t)m0 * 8 + tid * 2);
    *(f32x2*)(&lwk[tid * 2]) = v;
  }

  const f32x4 zero = {0.f, 0.f, 0.f, 0.f};
  f32x4 acc0[4][2];
  f32x4 acc1[4][2];
#pragma unroll
  for (int a = 0; a < 4; ++a)
#pragma unroll
    for (int b = 0; b < 2; ++b) { acc0[a][b] = zero; acc1[a][b] = zero; }

  const int ksteps = K / 32;
  const size_t aRow = (size_t)(m0 + srow) * K;
  const size_t bRow = (size_t)(n0 + srow) * K;

  for (int seg = 0; seg < 3; ++seg) {
    const ushort_t* As  = (seg == 1) ? A1  : A0;
    const ushort_t* B0s = (seg == 2) ? B01 : B00;
    const ushort_t* B1s = (seg == 2) ? B11 : B10;
    for (int s = 0; s < ksteps; ++s) {
      const int k0 = s * 32;
      __syncthreads();
      gload_lds16(As + aRow + k0 + skp, &lA[tid * 8]);
      gload_lds16(B0s + bRow + k0 + skp, &lB0[tid * 8]);
      if (NMATS == 2) gload_lds16(B1s + bRow + k0 + skp, &lB1[tid * 8]);
      __syncthreads();

      bf16x8 af[4], b0f[2], b1f[2];
#pragma unroll
      for (int fm = 0; fm < 4; ++fm)
        af[fm] = *(const bf16x8*)(&lA[(wr * 64 + fm * 16 + lrow) * 32 + kg]);
#pragma unroll
      for (int fn = 0; fn < 2; ++fn) {
        b0f[fn] = *(const bf16x8*)(&lB0[(wc * 32 + fn * 16 + lrow) * 32 + kg]);
        if (NMATS == 2)
          b1f[fn] = *(const bf16x8*)(&lB1[(wc * 32 + fn * 16 + lrow) * 32 + kg]);
      }
#pragma unroll
      for (int fm = 0; fm < 4; ++fm)
#pragma unroll
        for (int fn = 0; fn < 2; ++fn) {
          acc0[fm][fn] = __builtin_amdgcn_mfma_f32_16x16x32_bf16(af[fm], b0f[fn], acc0[fm][fn], 0, 0, 0);
          if (NMATS == 2)
            acc1[fm][fn] = __builtin_amdgcn_mfma_f32_16x16x32_bf16(af[fm], b1f[fn], acc1[fm][fn], 0, 0, 0);
        }
    }
  }

  const int r0f = (lane >> 4) * 4;
  const int ccf = lane & 15;

#pragma unroll
  for (int fm = 0; fm < 4; ++fm)
#pragma unroll
    for (int fn = 0; fn < 2; ++fn)
#pragma unroll
      for (int j = 0; j < 4; ++j) {
        int lrow_out = wr * 64 + fm * 16 + r0f + j;
        int grow = m0 + lrow_out;
        int gcol = n0 + wc * 32 + fn * 16 + ccf;
        size_t o = (size_t)grow * out_ld + gcol;
        if (EPI == 0) {
          Cf[o] = acc0[fm][fn][j];
        } else if (EPI == 1) {
          Cf[o] += acc0[fm][fn][j];
        } else if (EPI == 2) {
          float g = acc0[fm][fn][j], u = acc1[fm][fn][j];
          float h = g * (1.f / (1.f + __expf(-g))) * u;
          ushort_t hh = f2bf(h);
          Ohi[o] = hh;
          Olo[o] = f2bf(h - bf2f(hh));
        } else {  // EPI == 4
          float g = acc0[fm][fn][j], u = acc1[fm][fn][j];
          float h = g * (1.f / (1.f + __expf(-g))) * u;
          float wv = lwk[lrow_out * 8 + chunk];
          float prev = accum ? (bf2f(Ohi[o]) + bf2f(Olo[o])) : 0.f;
          float v = prev + wv * h;
          ushort_t hh = f2bf(v);
          Ohi[o] = hh;
          Olo[o] = f2bf(v - bf2f(hh));
        }
      }
}

// ---------------- host launcher ----------------
// Workspace plan (phase-overlapped; peak 120.25 MiB):
//   [0,32Mi)      xhi               (live: all GEMM A-sides until shared gate/up)
//   [32,64Mi)     xlo
//   [64,64.25Mi)  wkbuf             (live: router -> last moe chunk)
//   S = 64.25Mi scratch region:
//   Ph1 router:   wrt_hi/lo S+0/.5Mi, logits S+1..5Mi      (dead after k_router)
//   Ph2 moe:      cmb_hi S+0..16Mi, cmb_lo S+16..32Mi (RMW accumulator),
//                 chunk bufs wgtc/wutc hi+lo S+32..48Mi    (reused per chunk)
//   Ph4 moedown:  wdt hi/lo S+32..40Mi (cmb still live)
//   Ph5 shared:   sgtc/sutc S+0..16Mi, shhc S+16..48Mi, sdtc S+48..56Mi
extern "C" void kernel_launch(void* const* d_in, const int* in_sizes, int n_in,
                              void* d_out, int out_size, void* d_ws, size_t ws_size,
                              hipStream_t stream) {
  const float* x        = (const float*)d_in[0];
  const float* w_router = (const float*)d_in[1];
  const float* w_gate   = (const float*)d_in[2];
  const float* w_up     = (const float*)d_in[3];
  const float* w_down   = (const float*)d_in[4];
  const float* amps     = (const float*)d_in[5];
  const float* escale   = (const float*)d_in[6];
  const float* s_gate   = (const float*)d_in[7];
  const float* s_up     = (const float*)d_in[8];
  const float* s_down   = (const float*)d_in[9];
  float* out = (float*)d_out;

  const size_t MiB = 1024 * 1024;
  const size_t needed = 120 * MiB + 256 * 1024;   // 120.25 MiB peak
  if (ws_size < needed) return;  // fail loud via absmax (poisoned out), not a crash

  char* base = (char*)d_ws;
  ushort_t* xhi   = (ushort_t*)(base);
  ushort_t* xlo   = (ushort_t*)(base + 32 * MiB);
  float*    wkbuf = (float*)   (base + 64 * MiB);
  char* S = base + 64 * MiB + 256 * 1024;

  // Ph1
  ushort_t* wrt_hi = (ushort_t*)(S);
  ushort_t* wrt_lo = (ushort_t*)(S + 512 * 1024);
  float*    logits = (float*)   (S + 1 * MiB);
  // Ph2
  ushort_t* cmb_hi  = (ushort_t*)(S);
  ushort_t* cmb_lo  = (ushort_t*)(S + 16 * MiB);
  ushort_t* wgtc_hi = (ushort_t*)(S + 32 * MiB);
  ushort_t* wgtc_lo = (ushort_t*)(S + 36 * MiB);
  ushort_t* wutc_hi = (ushort_t*)(S + 40 * MiB);
  ushort_t* wutc_lo = (ushort_t*)(S + 44 * MiB);
  // Ph4
  ushort_t* wdt_hi = (ushort_t*)(S + 32 * MiB);
  ushort_t* wdt_lo = (ushort_t*)(S + 36 * MiB);
  // Ph5
  ushort_t* sgtc_hi = (ushort_t*)(S);
  ushort_t* sgtc_lo = (ushort_t*)(S + 4 * MiB);
  ushort_t* sutc_hi = (ushort_t*)(S + 8 * MiB);
  ushort_t* sutc_lo = (ushort_t*)(S + 12 * MiB);
  ushort_t* shhc_hi = (ushort_t*)(S + 16 * MiB);
  ushort_t* shhc_lo = (ushort_t*)(S + 32 * MiB);
  ushort_t* sdtc_hi = (ushort_t*)(S + 48 * MiB);
  ushort_t* sdtc_lo = (ushort_t*)(S + 52 * MiB);

  // --- Ph0: x -> hi/lo ---
  k_convert_split<<<2048, 256, 0, stream>>>(x, xhi, xlo, T_TOK * H_DIM / 4);

  // --- Ph1: router ---
  k_transpose_split<<<dim3(E_NUM / 32, H_DIM / 32), dim3(32, 8), 0, stream>>>(
      w_router, wrt_hi, wrt_lo, H_DIM, E_NUM);
  k_gemm<1, 0><<<dim3(T_TOK / 128, 1), 512, 0, stream>>>(
      xhi, xlo, wrt_hi, wrt_lo, nullptr, nullptr, nullptr,
      logits, nullptr, nullptr, H_DIM, E_NUM, 0, 0);
  k_router<<<T_TOK / 4, 256, 0, stream>>>(logits, amps, escale, wkbuf);

  // --- Ph2: moe gate/up + k-mix, one chunk (basis) at a time ---
  for (int c = 0; c < K_BASIS; ++c) {
    k_transpose_split<<<dim3(I_DIM / 32, H_DIM / 32), dim3(32, 8), 0, stream>>>(
        w_gate + c * I_DIM, wgtc_hi, wgtc_lo, H_DIM, K_BASIS * I_DIM);
    k_transpose_split<<<dim3(I_DIM / 32, H_DIM / 32), dim3(32, 8), 0, stream>>>(
        w_up + c * I_DIM, wutc_hi, wutc_lo, H_DIM, K_BASIS * I_DIM);
    k_gemm<2, 4><<<dim3(T_TOK / 128, I_DIM / 128), 512, 0, stream>>>(
        xhi, xlo, wgtc_hi, wgtc_lo, wutc_hi, wutc_lo, wkbuf,
        nullptr, cmb_hi, cmb_lo, H_DIM, I_DIM, c, (c > 0) ? 1 : 0);
  }

  // --- Ph4: moe down-projection -> out (first writer) ---
  k_transpose_split<<<dim3(H_DIM / 32, I_DIM / 32), dim3(32, 8), 0, stream>>>(
      w_down, wdt_hi, wdt_lo, I_DIM, H_DIM);
  k_gemm<1, 0><<<dim3(T_TOK / 128, H_DIM / 128), 512, 0, stream>>>(
      cmb_hi, cmb_lo, wdt_hi, wdt_lo, nullptr, nullptr, nullptr,
      out, nullptr, nullptr, I_DIM, H_DIM, 0, 0);

  // --- Ph5: shared expert, two 1024-column chunks of the 2I dim ---
  for (int n = 0; n < 2; ++n) {
    k_transpose_split<<<dim3(I_DIM / 32, H_DIM / 32), dim3(32, 8), 0, stream>>>(
        s_gate + n * I_DIM, sgtc_hi, sgtc_lo, H_DIM, 2 * I_DIM);
    k_transpose_split<<<dim3(I_DIM / 32, H_DIM / 32), dim3(32, 8), 0, stream>>>(
        s_up + n * I_DIM, sutc_hi, sutc_lo, H_DIM, 2 * I_DIM);
    k_gemm<2, 2><<<dim3(T_TOK / 128, I_DIM / 128), 512, 0, stream>>>(
        xhi, xlo, sgtc_hi, sgtc_lo, sutc_hi, sutc_lo, nullptr,
        nullptr, shhc_hi, shhc_lo, H_DIM, I_DIM, 0, 0);
    k_transpose_split<<<dim3(H_DIM / 32, I_DIM / 32), dim3(32, 8), 0, stream>>>(
        s_down + (size_t)n * I_DIM * H_DIM, sdtc_hi, sdtc_lo, I_DIM, H_DIM);
    k_gemm<1, 1><<<dim3(T_TOK / 128, H_DIM / 128), 512, 0, stream>>>(
        shhc_hi, shhc_lo, sdtc_hi, sdtc_lo, nullptr, nullptr, nullptr,
        out, nullptr, nullptr, I_DIM, H_DIM, 0, 0);
  }

  (void)in_sizes; (void)n_in; (void)out_size;
}